// Round 19
// baseline (332.526 us; speedup 1.0000x reference)
//
#include <hip/hip_runtime.h>

// VectorQuantizer: bf16-MFMA approximate distance pass + margin shortlist +
// exact f32 rescore + gather/losses.  N=32768, D=256, K=8192.
//
// R19 = R18 (321us) with vq_mfma moved to mfma_f32_32x32x16_bf16:
// one MFMA consumes a 1KB B-fragment against 32 reg-resident A-rows
// (vs 16) -> LDS-reads/FLOP halved; R18's wall was 56% LDS (2560 of
// 4556 cyc/chunk/CU). Config: BM=128 (wg4 x 32rows), chunk=128 (wn2 x
// ci2 x 32cands), NCH=64 (barriers halved), Bs 2x64KB -> 1 blk/CU,
// 2 waves/SIMD. VGPR ~122 < 128 cap (af 64 + acc 32 + cvv 8).
// Balanced pipes: LDS 2048+512 vs MFMA 2065 cyc/SIMD per chunk.
// D-layout (guide-verified): col=lane&31 (z-row), row=(reg&3)+8*(reg>>2)
// +4*(lane>>5) (cand). Schedule shape = R18-proven (post-barrier epi).

#define NROWS 32768
#define NE    8192
#define DDIM  256
#define BM    128
#define CAP   64
#define MARGIN 1e-4f
#define NCH   (NE / 128)   // 64 chunks of 128 candidates

typedef __attribute__((ext_vector_type(8)))  short bf16x8;
typedef __attribute__((ext_vector_type(16))) float f32x16;
typedef unsigned short u16;

__device__ __forceinline__ u16 f2bf(float f) {
  unsigned x = __float_as_uint(f);
  return (u16)((x + 0x7fffu + ((x >> 16) & 1u)) >> 16);   // RNE
}

__device__ __forceinline__ void gload_lds16(const void* g, void* l) {
  __builtin_amdgcn_global_load_lds(
      (const __attribute__((address_space(1))) void*)g,
      (__attribute__((address_space(3))) void*)l, 16, 0, 0);
}

// ---------------- row norms: a[n] = sum z^2, c[k] = sum e^2 -------------
__global__ __launch_bounds__(256)
void vq_norms(const float* __restrict__ z, const float* __restrict__ emb,
              float* __restrict__ arow, float* __restrict__ cemb) {
  int gid  = blockIdx.x * 256 + threadIdx.x;
  int wid  = gid >> 6;
  int lane = threadIdx.x & 63;
  const float* src;
  float* dst;
  if (wid < NROWS) { src = z + (size_t)wid * DDIM;   dst = arow + wid; }
  else             { int r = wid - NROWS;
                     src = emb + (size_t)r * DDIM;   dst = cemb + r; }
  float4 v = *reinterpret_cast<const float4*>(src + lane * 4);
  float s = v.x * v.x + v.y * v.y;
  s += v.z * v.z;
  s += v.w * v.w;
  #pragma unroll
  for (int off = 1; off < 64; off <<= 1) s += __shfl_xor(s, off, 64);
  if (lane == 0) *dst = s;
}

// -------- emb f32 -> bf16, FRAGMENT-MAJOR for 32x32x16 ------------------
// 16B-chunk o: frag = o>>6 (1KB), lane l = o&63.
// frag: g32 = frag>>4 (32-cand group), ks = frag&15 (K=16 step).
// lane holds cand (g32*32 + (l&31)), k-range [ks*16 + (l>>5)*8, +8).
__global__ __launch_bounds__(256)
void vq_cvt(const float* __restrict__ emb, u16* __restrict__ e16) {
  int o    = blockIdx.x * 256 + threadIdx.x;   // 0 .. NE*32-1
  int frag = o >> 6;
  int l    = o & 63;
  int g32  = frag >> 4;
  int ks   = frag & 15;
  int cand = g32 * 32 + (l & 31);
  int k    = ks * 16 + (l >> 5) * 8;
  const float* src = emb + (size_t)cand * DDIM + k;
  float4 v0 = *reinterpret_cast<const float4*>(src);
  float4 v1 = *reinterpret_cast<const float4*>(src + 4);
  u16 ov[8] = {f2bf(v0.x), f2bf(v0.y), f2bf(v0.z), f2bf(v0.w),
               f2bf(v1.x), f2bf(v1.y), f2bf(v1.z), f2bf(v1.w)};
  *reinterpret_cast<bf16x8*>(e16 + (size_t)o * 8) =
      *reinterpret_cast<bf16x8*>(ov);
}

// ---------------- MFMA approx pass + shortlist (32x32x16) ---------------
// 8 waves: wg=wid>>1 (4 x 32-row group), wn=wid&1 (2 x 64-cand half),
// ci in {0,1} picks the 32-cand quarter. Swapped operands
// mfma(cand_frag, zrow_frag): D col = z-row (lane&31), D row = cand.
__global__ __launch_bounds__(512)
void vq_mfma(const float* __restrict__ z, const u16* __restrict__ e16,
             const float* __restrict__ arow, const float* __restrict__ cemb,
             unsigned* __restrict__ cnt, int* __restrict__ list) {
  __shared__ u16 Bs[2][128 * DDIM];   // 2 x 64 KB, fragment-major

  const int t    = threadIdx.x;
  const int R0   = blockIdx.x * BM;
  const int lane = t & 63;
  const int wid  = t >> 6;          // 0..7
  const int wg   = wid >> 1;        // 0..3 : 32-row group
  const int wn   = wid & 1;         // 0..1 : 64-cand half
  const int l31  = lane & 31;
  const int lh   = lane >> 5;       // 0..1 : k-half / cand offset

  // ---- A fragments: z-row (R0+wg*32+l31), 16 K-steps in registers ----
  // af[s]: 8 bf16 = z[row][s*16 + lh*8 .. +8]
  bf16x8 af[16];
  const int row = R0 + wg * 32 + l31;
  {
    const float* zr = z + (size_t)row * DDIM;
    #pragma unroll
    for (int s = 0; s < 16; ++s) {
      const float* src = zr + s * 16 + lh * 8;
      float4 v0 = *reinterpret_cast<const float4*>(src);
      float4 v1 = *reinterpret_cast<const float4*>(src + 4);
      u16 o[8] = {f2bf(v0.x), f2bf(v0.y), f2bf(v0.z), f2bf(v0.w),
                  f2bf(v1.x), f2bf(v1.y), f2bf(v1.z), f2bf(v1.w)};
      af[s] = *reinterpret_cast<bf16x8*>(o);
    }
  }
  const float a_r = arow[row];
  float runmin = 3.4e38f;

  // ---- prologue: DMA chunk 0 -> Bs[0] (64 frags x 1KB; wave stages 8) ----
  {
    const char* src = (const char*)e16;
    #pragma unroll
    for (int i = 0; i < 8; ++i) {
      int f = wid * 8 + i;
      gload_lds16(src + f * 1024 + lane * 16, (char*)&Bs[0][0] + f * 1024);
    }
  }
  __syncthreads();   // drains prologue DMA

  for (int ch = 0; ch < NCH; ++ch) {
    const int buf = ch & 1;
    const int C0  = ch * 128;

    // ---- issue next chunk's DMA first (whole chunk to land) ----
    if (ch + 1 < NCH) {
      const char* src = (const char*)e16 + (size_t)(ch + 1) * 65536;
      char* dst = (char*)&Bs[buf ^ 1][0];
      #pragma unroll
      for (int i = 0; i < 8; ++i) {
        int f = wid * 8 + i;
        gload_lds16(src + f * 1024 + lane * 16, dst + f * 1024);
      }
    }

    // ---- hoisted epilogue constants (cand rows 0-3,8-11,16-19,24-27 +4*lh)
    float4 cvv[2][4];
    #pragma unroll
    for (int ci = 0; ci < 2; ++ci)
      #pragma unroll
      for (int q = 0; q < 4; ++q)
        cvv[ci][q] = *reinterpret_cast<const float4*>(
            &cemb[C0 + wn * 64 + ci * 32 + q * 8 + lh * 4]);

    // ---- compute: 16 K-steps x 2 ci, contiguous 1KB fragment reads ----
    f32x16 acc[2];
    #pragma unroll
    for (int ci = 0; ci < 2; ++ci)
      #pragma unroll
      for (int r = 0; r < 16; ++r) acc[ci][r] = 0.0f;

    const u16* Bp = &Bs[buf][0];
    #pragma unroll
    for (int s = 0; s < 16; ++s) {
      bf16x8 bfr[2];
      #pragma unroll
      for (int ci = 0; ci < 2; ++ci)
        bfr[ci] = *reinterpret_cast<const bf16x8*>(
            &Bp[(((wn * 2 + ci) * 16) + s) * 512 + lane * 8]);
      #pragma unroll
      for (int ci = 0; ci < 2; ++ci)
        acc[ci] = __builtin_amdgcn_mfma_f32_32x32x16_bf16(
            bfr[ci], af[s], acc[ci], 0, 0, 0);
    }

    __syncthreads();   // compute(buf) done by ALL waves; next DMA drained

    // ---- POST-BARRIER epilogue (regs + global only, no LDS) ----
    // lane's z-row = row; cand(ci,r) = C0+wn*64+ci*32+(r&3)+8*(r>>2)+4*lh
    float lm = 3.4e38f;
    #pragma unroll
    for (int ci = 0; ci < 2; ++ci)
      #pragma unroll
      for (int r = 0; r < 16; ++r) {
        float dd = fmaf(-2.0f, acc[ci][r], a_r) + cvv[ci][r >> 2][r & 3];
        lm = fminf(lm, dd);
      }
    float gm = fminf(lm, __shfl_xor(lm, 32, 64));
    runmin = fminf(runmin, gm);
    float thr = runmin + MARGIN;
    if (lm <= thr) {
      // u-form test (R5-verified): d<=thr <=> u >= 0.5*(a+c-thr)
      const float h = 0.5f * (a_r - thr);
      #pragma unroll
      for (int ci = 0; ci < 2; ++ci)
        #pragma unroll
        for (int r = 0; r < 16; ++r)
          if (acc[ci][r] >= fmaf(0.5f, cvv[ci][r >> 2][r & 3], h)) {
            int k = C0 + wn * 64 + ci * 32 + (r & 3) + 8 * (r >> 2) + 4 * lh;
            unsigned p = atomicAdd(&cnt[row], 1u);
            if (p < CAP) list[(size_t)row * CAP + p] = k;
          }
    }
  }
}

// ---------------- exact f32 rescore of shortlists (R15-verified) --------
__global__ __launch_bounds__(256)
void vq_rescore(const float* __restrict__ z, const float* __restrict__ emb,
                const float* __restrict__ arow, const float* __restrict__ cemb,
                const unsigned* __restrict__ cnt, const int* __restrict__ list,
                int* __restrict__ ws_idx) {
  const int row  = blockIdx.x * 4 + (threadIdx.x >> 6);
  const int lane = threadIdx.x & 63;
  const float a  = arow[row];
  const float4 zv = *reinterpret_cast<const float4*>(
      z + (size_t)row * DDIM + lane * 4);
  unsigned n = cnt[row];
  float bd = 3.4e38f;
  int   bk = 0;

  const bool fullscan = (n == 0 || n > CAP);
  const int  m = fullscan ? NE : (int)n;
  for (int i = 0; i < m; ++i) {
    int k = fullscan ? i : list[(size_t)row * CAP + i];
    const float4 ev = *reinterpret_cast<const float4*>(
        emb + (size_t)k * DDIM + lane * 4);
    float p = zv.x * ev.x;
    p = fmaf(zv.y, ev.y, p);
    p = fmaf(zv.z, ev.z, p);
    p = fmaf(zv.w, ev.w, p);
    #pragma unroll
    for (int off = 1; off < 64; off <<= 1) p += __shfl_xor(p, off, 64);
    float d = fmaf(-2.0f, p, a) + cemb[k];   // exact ref chain
    if (d < bd || (d == bd && k < bk)) { bd = d; bk = k; }
  }
  if (lane == 0) ws_idx[row] = bk;
}

// ---------------- gather + STE + losses (R16-verified, 64 rows/blk) -----
__global__ __launch_bounds__(256)
void vq_gather(const float* __restrict__ z, const float* __restrict__ emb,
               const int* __restrict__ ws_idx,
               float* __restrict__ out_zq, float* __restrict__ out_idx,
               double* __restrict__ loss_accum) {
  __shared__ float part[4];
  const int t  = threadIdx.x;
  const int R0 = blockIdx.x * 64;
  float lsum = 0.0f;
  for (int rr = 0; rr < 64; ++rr) {
    const int kb = ws_idx[R0 + rr];
    const size_t gi = (size_t)(R0 + rr) * DDIM + t;
    const float zv = z[gi];
    const float qv = emb[(size_t)kb * DDIM + t];
    const float diff = qv - zv;              // z_q - z
    out_zq[gi] = zv + diff;                  // z + (z_q - z) exact chain
    lsum = fmaf(diff, diff, lsum);
  }
  #pragma unroll
  for (int off = 1; off < 64; off <<= 1) lsum += __shfl_xor(lsum, off, 64);
  if ((t & 63) == 0) part[t >> 6] = lsum;
  __syncthreads();
  if (t == 0) {
    float tot = (part[0] + part[1]) + (part[2] + part[3]);
    atomicAdd(loss_accum, (double)tot);
  }
  if (t < 64) out_idx[R0 + t] = (float)ws_idx[R0 + t];
}

// ---------------- scalar losses -----------------------------------------
__global__ void vq_finalize(const double* __restrict__ loss_accum,
                            float* __restrict__ out_losses) {
  double m = *loss_accum / (double)((size_t)NROWS * DDIM);
  out_losses[0] = (float)(0.25 * m);   // loss_commit = BETA * mse
  out_losses[1] = (float)m;            // loss_codebook
}

extern "C" void kernel_launch(void* const* d_in, const int* in_sizes, int n_in,
                              void* d_out, int out_size, void* d_ws, size_t ws_size,
                              hipStream_t stream) {
  const float* z   = (const float*)d_in[0];
  const float* emb = (const float*)d_in[1];
  float* out        = (float*)d_out;
  float* out_zq     = out;                            // [8388608]
  float* out_losses = out + (size_t)NROWS * DDIM;     // [2]
  float* out_idx    = out + (size_t)NROWS * DDIM + 2; // [32768] as f32

  // persistent ws scratch (small)
  double* loss_accum = (double*)d_ws;
  float*  arow   = (float*)((char*)d_ws + 256);
  float*  cemb   = arow + NROWS;
  int*    ws_idx = (int*)(cemb + NE);

  // large scratch carved from d_out's z_q region (fully rewritten each call;
  // vq_gather overwrites only after rescore consumed list/cnt => safe)
  u16*      e16  = (u16*)d_out;                              // [0, 4MB)
  int*      list = (int*)((char*)d_out + (4 << 20));         // [4MB, 12MB) CAP=64
  unsigned* cnt  = (unsigned*)((char*)d_out + (12 << 20));   // [12MB, +128KB)

  hipMemsetAsync(d_ws, 0, 8, stream);
  hipMemsetAsync(cnt, 0, NROWS * sizeof(unsigned), stream);
  vq_norms<<<(NROWS + NE) / 4, 256, 0, stream>>>(z, emb, arow, cemb);
  vq_cvt<<<NE * 32 / 256, 256, 0, stream>>>(emb, e16);
  vq_mfma<<<NROWS / BM, 512, 0, stream>>>(z, e16, arow, cemb, cnt, list);
  vq_rescore<<<NROWS / 4, 256, 0, stream>>>(z, emb, arow, cemb, cnt, list, ws_idx);
  vq_gather<<<NROWS / 64, 256, 0, stream>>>(z, emb, ws_idx,
                                            out_zq, out_idx, loss_accum);
  vq_finalize<<<1, 1, 0, stream>>>(loss_accum, out_losses);
}